// Round 10
// baseline (334.864 us; speedup 1.0000x reference)
//
#include <hip/hip_runtime.h>

// Problem constants (match reference)
#define ED    32      // embedding / hidden dim
#define SEQ_T 200     // history length
#define NB    4096    // batch
#define H3    96      // 3*ED
#define IV    100001
#define PV    100001
#define DV    1001
#define PV_MAX 100000 // PV-1

typedef __attribute__((ext_vector_type(8))) short bf16x8;   // 8 bf16 (4 VGPRs)
typedef __attribute__((ext_vector_type(4))) float f32x4;    // MFMA acc

__device__ __forceinline__ float rcp_fast(float x) { return __builtin_amdgcn_rcpf(x); }
__device__ __forceinline__ float sigmoid_fast(float x) { return rcp_fast(1.0f + __expf(-x)); }
__device__ __forceinline__ float tanh_fast(float x) {
  const float e = __expf(-2.0f * x);
  return (1.0f - e) * rcp_fast(1.0f + e);
}

// round-to-nearest-even fp32 -> bf16 (as raw short)
__device__ __forceinline__ short bf16_rn(float v) {
  unsigned u = __float_as_uint(v);
  unsigned r = (u + 0x7fffu + ((u >> 16) & 1u)) >> 16;
  return (short)r;
}
__device__ __forceinline__ float bf16_f(short s) {
  return __uint_as_float(((unsigned)(unsigned short)s) << 16);
}

#define BCAST(v, K) \
  __uint_as_float((unsigned)__builtin_amdgcn_ds_swizzle((int)__float_as_uint(v), ((K) << 5)))

#define UNROLL32(M) \
  M(0)  M(1)  M(2)  M(3)  M(4)  M(5)  M(6)  M(7)  \
  M(8)  M(9)  M(10) M(11) M(12) M(13) M(14) M(15) \
  M(16) M(17) M(18) M(19) M(20) M(21) M(22) M(23) \
  M(24) M(25) M(26) M(27) M(28) M(29) M(30) M(31)

template <int TOWER>
__device__ __forceinline__ void fetch_idx(const int* __restrict__ ids,
                                          const float* __restrict__ prices,
                                          const int* __restrict__ depts,
                                          int base, int t, float pmean, float prsq,
                                          int& idx, bool& mk) {
  if constexpr (TOWER == 0) {
    idx = ids[base + t];
    mk = true;
  } else if constexpr (TOWER == 1) {
    const float p = prices[base + t];
    const float pn = (p - pmean) * prsq;
    mk = (pn != 0.0f);
    int q = (int)pn;
    q = q < 0 ? 0 : (q > PV_MAX ? PV_MAX : q);
    idx = q;
  } else {
    const int d = depts[base + t];
    mk = (d != 0);
    idx = d;
  }
}

// ---------------------------------------------------------------------------
// Phase 1: MFMA projection GEMM. XP[r][c] = table[r][:] @ Wx[:][c].
// One wave = 8 consecutive 16-row tiles of ONE table. Per tile:
//   A[m=l15][k=quad*8+j] = table[row0+m][k]    (2 x f32x4 contiguous loads)
//   B[k=quad*8+j][n=l15] = Wx[k][ct*16+n]      (loop-invariant, 6 col-tiles)
//   D[m=quad*4+rg][n=l15] -> XP[row0+m][ct*16+n]
// split-bf16: D = Ah*Bh + Ah*Bl + Al*Bh  (err ~2^-16, negligible).
// ---------------------------------------------------------------------------
#define TI ((IV + 15) / 16)   // 6251
#define TP ((PV + 15) / 16)   // 6251
#define TD ((DV + 15) / 16)   // 63
#define WI ((TI + 7) / 8)     // 782
#define WP ((TP + 7) / 8)     // 782
#define WD ((TD + 7) / 8)     // 8
#define PROJ_WAVES (WI + WP + WD)             // 1572
#define PROJ_BLOCKS ((PROJ_WAVES + 3) / 4)    // 393

__global__ void __launch_bounds__(256) proj_mfma(
    const float* __restrict__ item_table, const float* __restrict__ price_table,
    const float* __restrict__ dept_table,
    const float* __restrict__ item_Wx, const float* __restrict__ price_Wx,
    const float* __restrict__ dept_Wx,
    float* __restrict__ itemXP, float* __restrict__ priceXP,
    float* __restrict__ deptXP) {
  const int lane = threadIdx.x & 63;
  const int l15  = lane & 15;
  const int quad = lane >> 4;
  const int g    = blockIdx.x * 4 + (threadIdx.x >> 6);

  const float* table; const float* Wx; float* XP; int nrows; int lw;
  if (g < WI)            { table = item_table;  Wx = item_Wx;  XP = itemXP;  nrows = IV; lw = g; }
  else if (g < WI + WP)  { table = price_table; Wx = price_Wx; XP = priceXP; nrows = PV; lw = g - WI; }
  else if (g < PROJ_WAVES) { table = dept_table; Wx = dept_Wx; XP = deptXP; nrows = DV; lw = g - WI - WP; }
  else return;

  const int ntiles = (nrows + 15) >> 4;
  const int tile0  = lw * 8;
  if (tile0 >= ntiles) return;
  const int tile1  = min(tile0 + 8, ntiles);

  // Loop-invariant B fragments (Wx), hi/lo split.
  bf16x8 wbh[6], wbl[6];
#pragma unroll
  for (int ct = 0; ct < 6; ++ct) {
#pragma unroll
    for (int j = 0; j < 8; ++j) {
      const float w = Wx[(quad * 8 + j) * H3 + ct * 16 + l15];
      const short hi = bf16_rn(w);
      wbh[ct][j] = hi;
      wbl[ct][j] = bf16_rn(w - bf16_f(hi));
    }
  }

  // A prefetch for first tile.
  int rr = min(tile0 * 16 + l15, nrows - 1);
  f32x4 a0 = *(const f32x4*)(table + (size_t)rr * ED + quad * 8);
  f32x4 a1 = *(const f32x4*)(table + (size_t)rr * ED + quad * 8 + 4);

  for (int tt = tile0; tt < tile1; ++tt) {
    const f32x4 c0 = a0, c1 = a1;
    if (tt + 1 < tile1) {
      rr = min((tt + 1) * 16 + l15, nrows - 1);
      a0 = *(const f32x4*)(table + (size_t)rr * ED + quad * 8);
      a1 = *(const f32x4*)(table + (size_t)rr * ED + quad * 8 + 4);
    }

    bf16x8 ah, al;
#pragma unroll
    for (int j = 0; j < 4; ++j) {
      const short hi = bf16_rn(c0[j]);
      ah[j] = hi; al[j] = bf16_rn(c0[j] - bf16_f(hi));
    }
#pragma unroll
    for (int j = 0; j < 4; ++j) {
      const short hi = bf16_rn(c1[j]);
      ah[4 + j] = hi; al[4 + j] = bf16_rn(c1[j] - bf16_f(hi));
    }

    const int row0 = tt * 16;
    const bool full = (row0 + 16 <= nrows);
#pragma unroll
    for (int ct = 0; ct < 6; ++ct) {
      f32x4 acc = (f32x4)0.0f;
      acc = __builtin_amdgcn_mfma_f32_16x16x32_bf16(ah, wbh[ct], acc, 0, 0, 0);
      acc = __builtin_amdgcn_mfma_f32_16x16x32_bf16(ah, wbl[ct], acc, 0, 0, 0);
      acc = __builtin_amdgcn_mfma_f32_16x16x32_bf16(al, wbh[ct], acc, 0, 0, 0);
#pragma unroll
      for (int rg = 0; rg < 4; ++rg) {
        const int r = row0 + quad * 4 + rg;
        if (full || r < nrows)
          XP[(size_t)r * H3 + ct * 16 + l15] = acc[rg];
      }
    }
  }
}

// ---------------------------------------------------------------------------
// Phase 2: MFMA GRU, one wave = 16 batch rows, one wave per block,
// k-permuted operands (round-9 verified), DEPTH-2 gather prefetch:
// the XP index depends only on inputs (not h), so xq for step t+2 is issued
// during step t -> ~2 step-times (>1400 cyc) to cover L3 latency.
// ---------------------------------------------------------------------------
template <int TOWER>
__device__ void tower_mfma(const int* __restrict__ ids,
                           const float* __restrict__ prices,
                           const int* __restrict__ depts,
                           const float* __restrict__ XP,
                           const float* __restrict__ Wh,
                           const float* __restrict__ Bb,
                           float pmean, float prsq,
                           float* __restrict__ out) {
  const int lane = threadIdx.x & 63;
  const int l15  = lane & 15;
  const int quad = lane >> 4;
  const int grp  = blockIdx.x;
  const int bRow = grp * 16 + l15;
  const int base = bRow * SEQ_T;

  // Loop-invariant weight A-fragments, k-permuted:
  // pi(quad*8+j) = quad*4 + (j&3) + 16*(j>>2)  (matches D-layout residency).
  bf16x8 wa_hi[6], wa_lo[6];
#pragma unroll
  for (int tile = 0; tile < 6; ++tile) {
#pragma unroll
    for (int j = 0; j < 8; ++j) {
      const int kperm = quad * 4 + (j & 3) + 16 * (j >> 2);
      const float w = Wh[kperm * H3 + tile * 16 + l15];
      const short hi = bf16_rn(w);
      wa_hi[tile][j] = hi;
      wa_lo[tile][j] = bf16_rn(w - bf16_f(hi));
    }
  }

  // Per-lane bias vectors in D-layout (hidden = tl*16 + quad*4 + reg).
  f32x4 cz[2], cr[2], bi2[2], bh2[2];
#pragma unroll
  for (int tl = 0; tl < 2; ++tl) {
    const int h4 = tl * 16 + quad * 4;
    cz[tl]  = *(const f32x4*)(Bb + h4)      + *(const f32x4*)(Bb + 96 + h4);
    cr[tl]  = *(const f32x4*)(Bb + 32 + h4) + *(const f32x4*)(Bb + 128 + h4);
    bi2[tl] = *(const f32x4*)(Bb + 64 + h4);
    bh2[tl] = *(const f32x4*)(Bb + 160 + h4);
  }

  f32x4 hD[2];
  hD[0] = (f32x4)0.0f; hD[1] = (f32x4)0.0f;

  // Depth-2 prefetch pipeline.
  int iA, iB; bool mkA, mkB;
  f32x4 xqA[6], xqB[6];
  fetch_idx<TOWER>(ids, prices, depts, base, 0, pmean, prsq, iA, mkA);
#pragma unroll
  for (int tile = 0; tile < 6; ++tile)
    xqA[tile] = *(const f32x4*)(XP + (size_t)iA * H3 + tile * 16 + quad * 4);
  fetch_idx<TOWER>(ids, prices, depts, base, 1, pmean, prsq, iB, mkB);
#pragma unroll
  for (int tile = 0; tile < 6; ++tile)
    xqB[tile] = *(const f32x4*)(XP + (size_t)iB * H3 + tile * 16 + quad * 4);

#define GRU_STEP(XV, MK)                                                       \
  {                                                                            \
    bf16x8 hh, hl;                                                             \
    _Pragma("unroll")                                                          \
    for (int j = 0; j < 8; ++j) {                                              \
      const float v = hD[j >> 2][j & 3];                                       \
      const short hi = bf16_rn(v);                                             \
      hh[j] = hi;                                                              \
      hl[j] = bf16_rn(v - bf16_f(hi));                                         \
    }                                                                          \
    f32x4 acc[6];                                                              \
    acc[0] = XV[0] + cz[0];  acc[1] = XV[1] + cz[1];                           \
    acc[2] = XV[2] + cr[0];  acc[3] = XV[3] + cr[1];                           \
    acc[4] = bh2[0];         acc[5] = bh2[1];                                  \
    _Pragma("unroll")                                                          \
    for (int tile = 0; tile < 6; ++tile) {                                     \
      acc[tile] = __builtin_amdgcn_mfma_f32_16x16x32_bf16(wa_hi[tile], hh, acc[tile], 0, 0, 0); \
      acc[tile] = __builtin_amdgcn_mfma_f32_16x16x32_bf16(wa_hi[tile], hl, acc[tile], 0, 0, 0); \
      acc[tile] = __builtin_amdgcn_mfma_f32_16x16x32_bf16(wa_lo[tile], hh, acc[tile], 0, 0, 0); \
    }                                                                          \
    _Pragma("unroll")                                                          \
    for (int tl = 0; tl < 2; ++tl) {                                           \
      _Pragma("unroll")                                                        \
      for (int rg = 0; rg < 4; ++rg) {                                         \
        const float z  = sigmoid_fast(acc[tl][rg]);                            \
        const float r  = sigmoid_fast(acc[2 + tl][rg]);                        \
        const float gg = tanh_fast(XV[4 + tl][rg] + bi2[tl][rg] + r * acc[4 + tl][rg]); \
        const float hn = z * hD[tl][rg] + (1.0f - z) * gg;                     \
        hD[tl][rg] = (MK) ? hn : hD[tl][rg];                                   \
      }                                                                        \
    }                                                                          \
  }

  for (int t = 0; t < SEQ_T; t += 2) {
    // even step: consume xqA, refill xqA for t+2
    {
      f32x4 xv[6];
#pragma unroll
      for (int tile = 0; tile < 6; ++tile) xv[tile] = xqA[tile];
      const bool mk = mkA;
      if (t + 2 < SEQ_T) {
        fetch_idx<TOWER>(ids, prices, depts, base, t + 2, pmean, prsq, iA, mkA);
#pragma unroll
        for (int tile = 0; tile < 6; ++tile)
          xqA[tile] = *(const f32x4*)(XP + (size_t)iA * H3 + tile * 16 + quad * 4);
      }
      GRU_STEP(xv, mk)
    }
    // odd step: consume xqB, refill xqB for t+3
    {
      f32x4 xv[6];
#pragma unroll
      for (int tile = 0; tile < 6; ++tile) xv[tile] = xqB[tile];
      const bool mk = mkB;
      if (t + 3 < SEQ_T) {
        fetch_idx<TOWER>(ids, prices, depts, base, t + 3, pmean, prsq, iB, mkB);
#pragma unroll
        for (int tile = 0; tile < 6; ++tile)
          xqB[tile] = *(const f32x4*)(XP + (size_t)iB * H3 + tile * 16 + quad * 4);
      }
      GRU_STEP(xv, mk)
    }
  }
#undef GRU_STEP

#pragma unroll
  for (int tl = 0; tl < 2; ++tl)
    *(f32x4*)(out + (size_t)bRow * H3 + TOWER * ED + tl * 16 + quad * 4) = hD[tl];
}

__global__ void __launch_bounds__(64) gru_mfma(
    const int* __restrict__ ids, const float* __restrict__ prices, const int* __restrict__ depts,
    const float* __restrict__ itemXP, const float* __restrict__ priceXP,
    const float* __restrict__ deptXP,
    const float* __restrict__ item_Wh, const float* __restrict__ item_b,
    const float* __restrict__ price_Wh, const float* __restrict__ price_b,
    const float* __restrict__ dept_Wh, const float* __restrict__ dept_b,
    const float* __restrict__ price_mean, const float* __restrict__ price_var,
    float* __restrict__ out) {
  const int tower = blockIdx.y;
  if (tower == 0) {
    tower_mfma<0>(ids, prices, depts, itemXP, item_Wh, item_b, 0.0f, 0.0f, out);
  } else if (tower == 1) {
    const float pm = price_mean[0];
    const float pr = rsqrtf(price_var[0]);
    tower_mfma<1>(ids, prices, depts, priceXP, price_Wh, price_b, pm, pr, out);
  } else {
    tower_mfma<2>(ids, prices, depts, deptXP, dept_Wh, dept_b, 0.0f, 0.0f, out);
  }
}

// ---------------------------------------------------------------------------
// Fallback (ws too small): fused in-loop x@Wx (round-1 structure).
// ---------------------------------------------------------------------------
template <int TOWER>
__device__ void tower_run(const int* __restrict__ ids,
                          const float* __restrict__ prices,
                          const int* __restrict__ depts,
                          const float* __restrict__ table,
                          const float* __restrict__ Wx,
                          const float* __restrict__ Wh,
                          const float* __restrict__ Bb,
                          float pmean, float prsq,
                          float* __restrict__ out) {
  const int j    = threadIdx.x & 31;
  const int b    = blockIdx.x * 8 + (threadIdx.x >> 5);
  const int base = b * SEQ_T;

  float wx0[ED], wx1[ED], wx2[ED], wh0[ED], wh1[ED], wh2[ED];
#pragma unroll
  for (int k = 0; k < ED; ++k) {
    wx0[k] = Wx[k * H3 + j];
    wx1[k] = Wx[k * H3 + 32 + j];
    wx2[k] = Wx[k * H3 + 64 + j];
    wh0[k] = Wh[k * H3 + j];
    wh1[k] = Wh[k * H3 + 32 + j];
    wh2[k] = Wh[k * H3 + 64 + j];
  }
  const float bi0 = Bb[j],      bi1 = Bb[32 + j],  bi2 = Bb[64 + j];
  const float bh0 = Bb[96 + j], bh1 = Bb[128 + j], bh2 = Bb[160 + j];

  float h = 0.0f;
  int idx; bool mk_next;
  fetch_idx<TOWER>(ids, prices, depts, base, 0, pmean, prsq, idx, mk_next);
  float x_next = table[(size_t)idx * ED + j];

  for (int t = 0; t < SEQ_T; ++t) {
    const float xv = x_next;
    const bool  mk = mk_next;
    if (t + 1 < SEQ_T) {
      int idn;
      fetch_idx<TOWER>(ids, prices, depts, base, t + 1, pmean, prsq, idn, mk_next);
      x_next = table[(size_t)idn * ED + j];
    }

    float a0 = bi0, a1 = bi1, a2 = bi2;
    float r0 = bh0, r1 = bh1, r2 = bh2;
#define KSTEP(K)                              \
    {                                         \
      const float xk = BCAST(xv, K);          \
      const float hk = BCAST(h, K);           \
      a0 = __builtin_fmaf(xk, wx0[K], a0);    \
      a1 = __builtin_fmaf(xk, wx1[K], a1);    \
      a2 = __builtin_fmaf(xk, wx2[K], a2);    \
      r0 = __builtin_fmaf(hk, wh0[K], r0);    \
      r1 = __builtin_fmaf(hk, wh1[K], r1);    \
      r2 = __builtin_fmaf(hk, wh2[K], r2);    \
    }
    UNROLL32(KSTEP)
#undef KSTEP

    const float z  = sigmoid_fast(a0 + r0);
    const float r  = sigmoid_fast(a1 + r1);
    const float hc = tanh_fast(a2 + r * r2);
    const float hn = z * h + (1.0f - z) * hc;
    h = mk ? hn : h;
  }
  out[b * H3 + TOWER * ED + j] = h;
}

__global__ void __launch_bounds__(256, 2) gru_towers(
    const int* __restrict__ ids, const float* __restrict__ prices, const int* __restrict__ depts,
    const float* __restrict__ item_table, const float* __restrict__ price_table,
    const float* __restrict__ dept_table,
    const float* __restrict__ item_Wx, const float* __restrict__ item_Wh,
    const float* __restrict__ item_b,
    const float* __restrict__ price_Wx, const float* __restrict__ price_Wh,
    const float* __restrict__ price_b,
    const float* __restrict__ dept_Wx, const float* __restrict__ dept_Wh,
    const float* __restrict__ dept_b,
    const float* __restrict__ price_mean, const float* __restrict__ price_var,
    float* __restrict__ out) {
  const int tower = blockIdx.y;
  if (tower == 0) {
    tower_run<0>(ids, prices, depts, item_table, item_Wx, item_Wh, item_b, 0.0f, 0.0f, out);
  } else if (tower == 1) {
    const float pm = price_mean[0];
    const float pr = rsqrtf(price_var[0]);
    tower_run<1>(ids, prices, depts, price_table, price_Wx, price_Wh, price_b, pm, pr, out);
  } else {
    tower_run<2>(ids, prices, depts, dept_table, dept_Wx, dept_Wh, dept_b, 0.0f, 0.0f, out);
  }
}

extern "C" void kernel_launch(void* const* d_in, const int* in_sizes, int n_in,
                              void* d_out, int out_size, void* d_ws, size_t ws_size,
                              hipStream_t stream) {
  const int*   ids         = (const int*)d_in[0];
  const float* prices      = (const float*)d_in[1];
  const int*   depts       = (const int*)d_in[2];
  const float* item_table  = (const float*)d_in[3];
  const float* price_table = (const float*)d_in[4];
  const float* dept_table  = (const float*)d_in[5];
  const float* item_Wx     = (const float*)d_in[6];
  const float* item_Wh     = (const float*)d_in[7];
  const float* item_b      = (const float*)d_in[8];
  const float* price_Wx    = (const float*)d_in[9];
  const float* price_Wh    = (const float*)d_in[10];
  const float* price_b     = (const float*)d_in[11];
  const float* dept_Wx     = (const float*)d_in[12];
  const float* dept_Wh     = (const float*)d_in[13];
  const float* dept_b      = (const float*)d_in[14];
  const float* price_mean  = (const float*)d_in[15];
  const float* price_var   = (const float*)d_in[16];
  float* out = (float*)d_out;

  const size_t need = (size_t)(IV + PV + DV) * H3 * sizeof(float);
  if (ws_size >= need) {
    float* itemXP  = (float*)d_ws;
    float* priceXP = itemXP + (size_t)IV * H3;
    float* deptXP  = priceXP + (size_t)PV * H3;

    proj_mfma<<<dim3(PROJ_BLOCKS), 256, 0, stream>>>(
        item_table, price_table, dept_table,
        item_Wx, price_Wx, dept_Wx,
        itemXP, priceXP, deptXP);

    dim3 grid(NB / 16, 3, 1);   // one wave per block
    gru_mfma<<<grid, 64, 0, stream>>>(
        ids, prices, depts, itemXP, priceXP, deptXP,
        item_Wh, item_b, price_Wh, price_b, dept_Wh, dept_b,
        price_mean, price_var, out);
  } else {
    dim3 grid(NB / 8, 3, 1);
    gru_towers<<<grid, 256, 0, stream>>>(
        ids, prices, depts, item_table, price_table, dept_table,
        item_Wx, item_Wh, item_b, price_Wx, price_Wh, price_b,
        dept_Wx, dept_Wh, dept_b, price_mean, price_var, out);
  }
}

// Round 11
// 301.669 us; speedup vs baseline: 1.1100x; 1.1100x over previous
//
#include <hip/hip_runtime.h>

// Problem constants (match reference)
#define ED    32      // embedding / hidden dim
#define SEQ_T 200     // history length
#define NB    4096    // batch
#define H3    96      // 3*ED
#define IV    100001
#define PV    100001
#define DV    1001
#define PV_MAX 100000 // PV-1

typedef __attribute__((ext_vector_type(8))) short bf16x8;   // 8 bf16 (4 VGPRs)
typedef __attribute__((ext_vector_type(4))) float f32x4;    // MFMA acc

__device__ __forceinline__ float rcp_fast(float x) { return __builtin_amdgcn_rcpf(x); }
__device__ __forceinline__ float sigmoid_fast(float x) { return rcp_fast(1.0f + __expf(-x)); }
__device__ __forceinline__ float tanh_fast(float x) {
  const float e = __expf(-2.0f * x);
  return (1.0f - e) * rcp_fast(1.0f + e);
}

// round-to-nearest-even fp32 -> bf16 (as raw short)
__device__ __forceinline__ short bf16_rn(float v) {
  unsigned u = __float_as_uint(v);
  unsigned r = (u + 0x7fffu + ((u >> 16) & 1u)) >> 16;
  return (short)r;
}
__device__ __forceinline__ float bf16_f(short s) {
  return __uint_as_float(((unsigned)(unsigned short)s) << 16);
}

template <int TOWER>
__device__ __forceinline__ void fetch_idx(const int* __restrict__ ids,
                                          const float* __restrict__ prices,
                                          const int* __restrict__ depts,
                                          int base, int t, float pmean, float prsq,
                                          int& idx, bool& mk) {
  if constexpr (TOWER == 0) {
    idx = ids[base + t];
    mk = true;
  } else if constexpr (TOWER == 1) {
    const float p = prices[base + t];
    const float pn = (p - pmean) * prsq;
    mk = (pn != 0.0f);
    int q = (int)pn;
    q = q < 0 ? 0 : (q > PV_MAX ? PV_MAX : q);
    idx = q;
  } else {
    const int d = depts[base + t];
    mk = (d != 0);
    idx = d;
  }
}

// ---------------------------------------------------------------------------
// Fully fused GRU: one wave = 16 batch rows of one tower; no XP workspace.
// Per step (all on the matrix pipe, split-bf16 hi/lo, drop lo*lo):
//   xp  = Wx^T @ emb^T   A[m=l15][k=quad*8+j]=Wx[k][m-tile]  (natural k)
//                        B[k=quad*8+j][n=l15]=emb[row(n)][k] (contiguous 32B/lane)
//   rec = Wh^T @ h^T     k-PERMUTED (round-9): pi(quad*8+j)=quad*4+(j&3)+16*(j>>2)
//                        -> next-step h B-frag built IN-LANE from hD, no LDS.
//   D-layout for both:   D[m=tl*16+quad*4+rg][n=l15], batch = l15.
// Gates in D-layout; 36 MFMAs/step; emb gather = 2 lines/row (vs 6 for XP).
// Weight fragments are MFMA-only operands -> AGPR residency is free.
// ---------------------------------------------------------------------------
template <int TOWER>
__device__ void tower_fused(const int* __restrict__ ids,
                            const float* __restrict__ prices,
                            const int* __restrict__ depts,
                            const float* __restrict__ emb,
                            const float* __restrict__ Wx,
                            const float* __restrict__ Wh,
                            const float* __restrict__ Bb,
                            float pmean, float prsq,
                            float* __restrict__ out) {
  const int lane = threadIdx.x & 63;
  const int l15  = lane & 15;
  const int quad = lane >> 4;
  const int bRow = blockIdx.x * 16 + l15;
  const int base = bRow * SEQ_T;

  // Wh A-fragments, k-permuted (verified round 9).
  bf16x8 wh_hi[6], wh_lo[6];
#pragma unroll
  for (int tile = 0; tile < 6; ++tile) {
#pragma unroll
    for (int j = 0; j < 8; ++j) {
      const int kperm = quad * 4 + (j & 3) + 16 * (j >> 2);
      const float w = Wh[kperm * H3 + tile * 16 + l15];
      const short hi = bf16_rn(w);
      wh_hi[tile][j] = hi;
      wh_lo[tile][j] = bf16_rn(w - bf16_f(hi));
    }
  }
  // Wx A-fragments, natural k (matches emb B natural-k contiguous load).
  bf16x8 wx_hi[6], wx_lo[6];
#pragma unroll
  for (int tile = 0; tile < 6; ++tile) {
#pragma unroll
    for (int j = 0; j < 8; ++j) {
      const float w = Wx[(quad * 8 + j) * H3 + tile * 16 + l15];
      const short hi = bf16_rn(w);
      wx_hi[tile][j] = hi;
      wx_lo[tile][j] = bf16_rn(w - bf16_f(hi));
    }
  }

  // Bias vectors in D-layout (hidden = tl*16 + quad*4 + rg).
  f32x4 cz[2], cr[2], bi2v[2], bh2v[2];
#pragma unroll
  for (int tl = 0; tl < 2; ++tl) {
    const int h4 = tl * 16 + quad * 4;
    cz[tl]   = *(const f32x4*)(Bb + h4)      + *(const f32x4*)(Bb + 96 + h4);
    cr[tl]   = *(const f32x4*)(Bb + 32 + h4) + *(const f32x4*)(Bb + 128 + h4);
    bi2v[tl] = *(const f32x4*)(Bb + 64 + h4);
    bh2v[tl] = *(const f32x4*)(Bb + 160 + h4);
  }

  f32x4 hD[2];
  hD[0] = (f32x4)0.0f; hD[1] = (f32x4)0.0f;

  // Depth-1 emb prefetch (round-9 proven structure; depth-2 regressed r10).
  int idx; bool mk_next;
  fetch_idx<TOWER>(ids, prices, depts, base, 0, pmean, prsq, idx, mk_next);
  f32x4 e0 = *(const f32x4*)(emb + (size_t)idx * ED + quad * 8);
  f32x4 e1 = *(const f32x4*)(emb + (size_t)idx * ED + quad * 8 + 4);

  for (int t = 0; t < SEQ_T; ++t) {
    const f32x4 c0 = e0, c1 = e1;
    const bool  mk = mk_next;
    if (t + 1 < SEQ_T) {
      int idn;
      fetch_idx<TOWER>(ids, prices, depts, base, t + 1, pmean, prsq, idn, mk_next);
      e0 = *(const f32x4*)(emb + (size_t)idn * ED + quad * 8);
      e1 = *(const f32x4*)(emb + (size_t)idn * ED + quad * 8 + 4);
    }

    // emb B-fragment (split hi/lo).
    bf16x8 ebh, ebl;
#pragma unroll
    for (int j = 0; j < 4; ++j) {
      const short hi = bf16_rn(c0[j]);
      ebh[j] = hi; ebl[j] = bf16_rn(c0[j] - bf16_f(hi));
    }
#pragma unroll
    for (int j = 0; j < 4; ++j) {
      const short hi = bf16_rn(c1[j]);
      ebh[4 + j] = hi; ebl[4 + j] = bf16_rn(c1[j] - bf16_f(hi));
    }
    // h B-fragment, in-lane via k-permutation (split hi/lo).
    bf16x8 hh, hl;
#pragma unroll
    for (int j = 0; j < 8; ++j) {
      const float v = hD[j >> 2][j & 3];
      const short hi = bf16_rn(v);
      hh[j] = hi;
      hl[j] = bf16_rn(v - bf16_f(hi));
    }

    // Accumulators: z, r get xp+rec+both biases; h-gate keeps xp and rec apart.
    f32x4 az[2], ar[2], axh[2], arh[2];
#pragma unroll
    for (int tl = 0; tl < 2; ++tl) {
      az[tl]  = cz[tl];
      ar[tl]  = cr[tl];
      axh[tl] = bi2v[tl];
      arh[tl] = bh2v[tl];
      // xp contributions (Wx @ emb)
      az[tl]  = __builtin_amdgcn_mfma_f32_16x16x32_bf16(wx_hi[tl],     ebh, az[tl], 0, 0, 0);
      az[tl]  = __builtin_amdgcn_mfma_f32_16x16x32_bf16(wx_hi[tl],     ebl, az[tl], 0, 0, 0);
      az[tl]  = __builtin_amdgcn_mfma_f32_16x16x32_bf16(wx_lo[tl],     ebh, az[tl], 0, 0, 0);
      ar[tl]  = __builtin_amdgcn_mfma_f32_16x16x32_bf16(wx_hi[2 + tl], ebh, ar[tl], 0, 0, 0);
      ar[tl]  = __builtin_amdgcn_mfma_f32_16x16x32_bf16(wx_hi[2 + tl], ebl, ar[tl], 0, 0, 0);
      ar[tl]  = __builtin_amdgcn_mfma_f32_16x16x32_bf16(wx_lo[2 + tl], ebh, ar[tl], 0, 0, 0);
      axh[tl] = __builtin_amdgcn_mfma_f32_16x16x32_bf16(wx_hi[4 + tl], ebh, axh[tl], 0, 0, 0);
      axh[tl] = __builtin_amdgcn_mfma_f32_16x16x32_bf16(wx_hi[4 + tl], ebl, axh[tl], 0, 0, 0);
      axh[tl] = __builtin_amdgcn_mfma_f32_16x16x32_bf16(wx_lo[4 + tl], ebh, axh[tl], 0, 0, 0);
      // rec contributions (Wh @ h)
      az[tl]  = __builtin_amdgcn_mfma_f32_16x16x32_bf16(wh_hi[tl],     hh, az[tl], 0, 0, 0);
      az[tl]  = __builtin_amdgcn_mfma_f32_16x16x32_bf16(wh_hi[tl],     hl, az[tl], 0, 0, 0);
      az[tl]  = __builtin_amdgcn_mfma_f32_16x16x32_bf16(wh_lo[tl],     hh, az[tl], 0, 0, 0);
      ar[tl]  = __builtin_amdgcn_mfma_f32_16x16x32_bf16(wh_hi[2 + tl], hh, ar[tl], 0, 0, 0);
      ar[tl]  = __builtin_amdgcn_mfma_f32_16x16x32_bf16(wh_hi[2 + tl], hl, ar[tl], 0, 0, 0);
      ar[tl]  = __builtin_amdgcn_mfma_f32_16x16x32_bf16(wh_lo[2 + tl], hh, ar[tl], 0, 0, 0);
      arh[tl] = __builtin_amdgcn_mfma_f32_16x16x32_bf16(wh_hi[4 + tl], hh, arh[tl], 0, 0, 0);
      arh[tl] = __builtin_amdgcn_mfma_f32_16x16x32_bf16(wh_hi[4 + tl], hl, arh[tl], 0, 0, 0);
      arh[tl] = __builtin_amdgcn_mfma_f32_16x16x32_bf16(wh_lo[4 + tl], hh, arh[tl], 0, 0, 0);
    }

    // Gates (batch = l15, hidden = tl*16 + quad*4 + rg).
#pragma unroll
    for (int tl = 0; tl < 2; ++tl) {
#pragma unroll
      for (int rg = 0; rg < 4; ++rg) {
        const float z  = sigmoid_fast(az[tl][rg]);
        const float r  = sigmoid_fast(ar[tl][rg]);
        const float g  = tanh_fast(axh[tl][rg] + r * arh[tl][rg]);
        const float hn = z * hD[tl][rg] + (1.0f - z) * g;
        hD[tl][rg] = mk ? hn : hD[tl][rg];
      }
    }
  }

#pragma unroll
  for (int tl = 0; tl < 2; ++tl)
    *(f32x4*)(out + (size_t)bRow * H3 + TOWER * ED + tl * 16 + quad * 4) = hD[tl];
}

__global__ void __launch_bounds__(64) gru_fused(
    const int* __restrict__ ids, const float* __restrict__ prices, const int* __restrict__ depts,
    const float* __restrict__ item_table, const float* __restrict__ price_table,
    const float* __restrict__ dept_table,
    const float* __restrict__ item_Wx, const float* __restrict__ item_Wh,
    const float* __restrict__ item_b,
    const float* __restrict__ price_Wx, const float* __restrict__ price_Wh,
    const float* __restrict__ price_b,
    const float* __restrict__ dept_Wx, const float* __restrict__ dept_Wh,
    const float* __restrict__ dept_b,
    const float* __restrict__ price_mean, const float* __restrict__ price_var,
    float* __restrict__ out) {
  const int tower = blockIdx.y;
  if (tower == 0) {
    tower_fused<0>(ids, prices, depts, item_table, item_Wx, item_Wh, item_b,
                   0.0f, 0.0f, out);
  } else if (tower == 1) {
    const float pm = price_mean[0];
    const float pr = rsqrtf(price_var[0]);
    tower_fused<1>(ids, prices, depts, price_table, price_Wx, price_Wh, price_b,
                   pm, pr, out);
  } else {
    tower_fused<2>(ids, prices, depts, dept_table, dept_Wx, dept_Wh, dept_b,
                   0.0f, 0.0f, out);
  }
}

extern "C" void kernel_launch(void* const* d_in, const int* in_sizes, int n_in,
                              void* d_out, int out_size, void* d_ws, size_t ws_size,
                              hipStream_t stream) {
  const int*   ids         = (const int*)d_in[0];
  const float* prices      = (const float*)d_in[1];
  const int*   depts       = (const int*)d_in[2];
  const float* item_table  = (const float*)d_in[3];
  const float* price_table = (const float*)d_in[4];
  const float* dept_table  = (const float*)d_in[5];
  const float* item_Wx     = (const float*)d_in[6];
  const float* item_Wh     = (const float*)d_in[7];
  const float* item_b      = (const float*)d_in[8];
  const float* price_Wx    = (const float*)d_in[9];
  const float* price_Wh    = (const float*)d_in[10];
  const float* price_b     = (const float*)d_in[11];
  const float* dept_Wx     = (const float*)d_in[12];
  const float* dept_Wh     = (const float*)d_in[13];
  const float* dept_b      = (const float*)d_in[14];
  const float* price_mean  = (const float*)d_in[15];
  const float* price_var   = (const float*)d_in[16];
  float* out = (float*)d_out;

  dim3 grid(NB / 16, 3, 1);   // one wave per block; 768 single-wave blocks
  gru_fused<<<grid, 64, 0, stream>>>(
      ids, prices, depts, item_table, price_table, dept_table,
      item_Wx, item_Wh, item_b, price_Wx, price_Wh, price_b,
      dept_Wx, dept_Wh, dept_b, price_mean, price_var, out);
}

// Round 12
// 290.939 us; speedup vs baseline: 1.1510x; 1.0369x over previous
//
#include <hip/hip_runtime.h>

// Problem constants (match reference)
#define ED    32      // embedding / hidden dim
#define SEQ_T 200     // history length
#define NB    4096    // batch
#define H3    96      // 3*ED
#define IV    100001
#define PV    100001
#define DV    1001
#define PV_MAX 100000 // PV-1

typedef __attribute__((ext_vector_type(8))) short bf16x8;   // 8 bf16 (4 VGPRs)
typedef __attribute__((ext_vector_type(4))) float f32x4;    // MFMA acc
typedef __attribute__((ext_vector_type(4))) int   i32x4;

__device__ __forceinline__ float rcp_fast(float x) { return __builtin_amdgcn_rcpf(x); }
__device__ __forceinline__ float sigmoid_fast(float x) { return rcp_fast(1.0f + __expf(-x)); }
__device__ __forceinline__ float tanh_fast(float x) {
  const float e = __expf(-2.0f * x);
  return (1.0f - e) * rcp_fast(1.0f + e);
}

// round-to-nearest-even fp32 -> bf16 (weights only; one-time cost)
__device__ __forceinline__ short bf16_rn(float v) {
  unsigned u = __float_as_uint(v);
  unsigned r = (u + 0x7fffu + ((u >> 16) & 1u)) >> 16;
  return (short)r;
}
__device__ __forceinline__ float bf16_f(short s) {
  return __uint_as_float(((unsigned)(unsigned short)s) << 16);
}

// Cheap split of 8 fp32 -> (hi, lo) bf16x8 fragments.
// hi = truncate-to-bf16(v) (its error lands in lo exactly); lo truncated too
// (residual ~2^-17 rel). Pack 2 shorts per VGPR with one v_perm_b32.
// Cost: 8 and + 8 sub + 8 perm = 24 VALU for 8 values (vs ~80 for RNE splits).
union I4B8 { i32x4 i; bf16x8 b; };
__device__ __forceinline__ void split_pack8(const f32x4 c0, const f32x4 c1,
                                            bf16x8& vh, bf16x8& vl) {
  float v[8] = {c0[0], c0[1], c0[2], c0[3], c1[0], c1[1], c1[2], c1[3]};
  float lo[8];
#pragma unroll
  for (int i = 0; i < 8; ++i) {
    const float hif = __uint_as_float(__float_as_uint(v[i]) & 0xffff0000u);
    lo[i] = v[i] - hif;
  }
  I4B8 H, L;
#pragma unroll
  for (int i = 0; i < 4; ++i) {
    H.i[i] = (int)__builtin_amdgcn_perm(__float_as_uint(v[2 * i + 1]),
                                        __float_as_uint(v[2 * i]), 0x07060302u);
    L.i[i] = (int)__builtin_amdgcn_perm(__float_as_uint(lo[2 * i + 1]),
                                        __float_as_uint(lo[2 * i]), 0x07060302u);
  }
  vh = H.b; vl = L.b;
}

template <int TOWER>
__device__ __forceinline__ void fetch_idx(const int* __restrict__ ids,
                                          const float* __restrict__ prices,
                                          const int* __restrict__ depts,
                                          int base, int t, float pmean, float prsq,
                                          int& idx, bool& mk) {
  if constexpr (TOWER == 0) {
    idx = ids[base + t];
    mk = true;
  } else if constexpr (TOWER == 1) {
    const float p = prices[base + t];
    const float pn = (p - pmean) * prsq;
    mk = (pn != 0.0f);
    int q = (int)pn;
    q = q < 0 ? 0 : (q > PV_MAX ? PV_MAX : q);
    idx = q;
  } else {
    const int d = depts[base + t];
    mk = (d != 0);
    idx = d;
  }
}

// ---------------------------------------------------------------------------
// Fully fused GRU (round-11 structure + cheap splits).
// One wave = 16 batch rows; xp and rec both on the matrix pipe per step;
// h B-fragment in-lane via k-permutation (round-9); depth-1 emb prefetch.
// ---------------------------------------------------------------------------
template <int TOWER>
__device__ void tower_fused(const int* __restrict__ ids,
                            const float* __restrict__ prices,
                            const int* __restrict__ depts,
                            const float* __restrict__ emb,
                            const float* __restrict__ Wx,
                            const float* __restrict__ Wh,
                            const float* __restrict__ Bb,
                            float pmean, float prsq,
                            float* __restrict__ out) {
  const int lane = threadIdx.x & 63;
  const int l15  = lane & 15;
  const int quad = lane >> 4;
  const int bRow = blockIdx.x * 16 + l15;
  const int base = bRow * SEQ_T;

  // Wh A-fragments, k-permuted: pi(quad*8+j) = quad*4 + (j&3) + 16*(j>>2).
  bf16x8 wh_hi[6], wh_lo[6];
#pragma unroll
  for (int tile = 0; tile < 6; ++tile) {
#pragma unroll
    for (int j = 0; j < 8; ++j) {
      const int kperm = quad * 4 + (j & 3) + 16 * (j >> 2);
      const float w = Wh[kperm * H3 + tile * 16 + l15];
      const short hi = bf16_rn(w);
      wh_hi[tile][j] = hi;
      wh_lo[tile][j] = bf16_rn(w - bf16_f(hi));
    }
  }
  // Wx A-fragments, natural k.
  bf16x8 wx_hi[6], wx_lo[6];
#pragma unroll
  for (int tile = 0; tile < 6; ++tile) {
#pragma unroll
    for (int j = 0; j < 8; ++j) {
      const float w = Wx[(quad * 8 + j) * H3 + tile * 16 + l15];
      const short hi = bf16_rn(w);
      wx_hi[tile][j] = hi;
      wx_lo[tile][j] = bf16_rn(w - bf16_f(hi));
    }
  }

  // Bias vectors in D-layout (hidden = tl*16 + quad*4 + rg).
  f32x4 cz[2], cr[2], bi2v[2], bh2v[2];
#pragma unroll
  for (int tl = 0; tl < 2; ++tl) {
    const int h4 = tl * 16 + quad * 4;
    cz[tl]   = *(const f32x4*)(Bb + h4)      + *(const f32x4*)(Bb + 96 + h4);
    cr[tl]   = *(const f32x4*)(Bb + 32 + h4) + *(const f32x4*)(Bb + 128 + h4);
    bi2v[tl] = *(const f32x4*)(Bb + 64 + h4);
    bh2v[tl] = *(const f32x4*)(Bb + 160 + h4);
  }

  f32x4 hD[2];
  hD[0] = (f32x4)0.0f; hD[1] = (f32x4)0.0f;

  // Depth-1 emb prefetch.
  int idx; bool mk_next;
  fetch_idx<TOWER>(ids, prices, depts, base, 0, pmean, prsq, idx, mk_next);
  f32x4 e0 = *(const f32x4*)(emb + (size_t)idx * ED + quad * 8);
  f32x4 e1 = *(const f32x4*)(emb + (size_t)idx * ED + quad * 8 + 4);

  for (int t = 0; t < SEQ_T; ++t) {
    const f32x4 c0 = e0, c1 = e1;
    const bool  mk = mk_next;
    if (t + 1 < SEQ_T) {
      int idn;
      fetch_idx<TOWER>(ids, prices, depts, base, t + 1, pmean, prsq, idn, mk_next);
      e0 = *(const f32x4*)(emb + (size_t)idn * ED + quad * 8);
      e1 = *(const f32x4*)(emb + (size_t)idn * ED + quad * 8 + 4);
    }

    // emb B-fragment (cheap split).
    bf16x8 ebh, ebl;
    split_pack8(c0, c1, ebh, ebl);
    // h B-fragment, in-lane via k-permutation (cheap split).
    bf16x8 hh, hl;
    split_pack8(hD[0], hD[1], hh, hl);

    // Accumulators: z, r get both biases; h-gate keeps xp and rec apart.
    f32x4 az[2], ar[2], axh[2], arh[2];
#pragma unroll
    for (int tl = 0; tl < 2; ++tl) {
      az[tl]  = cz[tl];
      ar[tl]  = cr[tl];
      axh[tl] = bi2v[tl];
      arh[tl] = bh2v[tl];
      // xp contributions (Wx @ emb)
      az[tl]  = __builtin_amdgcn_mfma_f32_16x16x32_bf16(wx_hi[tl],     ebh, az[tl], 0, 0, 0);
      az[tl]  = __builtin_amdgcn_mfma_f32_16x16x32_bf16(wx_hi[tl],     ebl, az[tl], 0, 0, 0);
      az[tl]  = __builtin_amdgcn_mfma_f32_16x16x32_bf16(wx_lo[tl],     ebh, az[tl], 0, 0, 0);
      ar[tl]  = __builtin_amdgcn_mfma_f32_16x16x32_bf16(wx_hi[2 + tl], ebh, ar[tl], 0, 0, 0);
      ar[tl]  = __builtin_amdgcn_mfma_f32_16x16x32_bf16(wx_hi[2 + tl], ebl, ar[tl], 0, 0, 0);
      ar[tl]  = __builtin_amdgcn_mfma_f32_16x16x32_bf16(wx_lo[2 + tl], ebh, ar[tl], 0, 0, 0);
      axh[tl] = __builtin_amdgcn_mfma_f32_16x16x32_bf16(wx_hi[4 + tl], ebh, axh[tl], 0, 0, 0);
      axh[tl] = __builtin_amdgcn_mfma_f32_16x16x32_bf16(wx_hi[4 + tl], ebl, axh[tl], 0, 0, 0);
      axh[tl] = __builtin_amdgcn_mfma_f32_16x16x32_bf16(wx_lo[4 + tl], ebh, axh[tl], 0, 0, 0);
      // rec contributions (Wh @ h)
      az[tl]  = __builtin_amdgcn_mfma_f32_16x16x32_bf16(wh_hi[tl],     hh, az[tl], 0, 0, 0);
      az[tl]  = __builtin_amdgcn_mfma_f32_16x16x32_bf16(wh_hi[tl],     hl, az[tl], 0, 0, 0);
      az[tl]  = __builtin_amdgcn_mfma_f32_16x16x32_bf16(wh_lo[tl],     hh, az[tl], 0, 0, 0);
      ar[tl]  = __builtin_amdgcn_mfma_f32_16x16x32_bf16(wh_hi[2 + tl], hh, ar[tl], 0, 0, 0);
      ar[tl]  = __builtin_amdgcn_mfma_f32_16x16x32_bf16(wh_hi[2 + tl], hl, ar[tl], 0, 0, 0);
      ar[tl]  = __builtin_amdgcn_mfma_f32_16x16x32_bf16(wh_lo[2 + tl], hh, ar[tl], 0, 0, 0);
      arh[tl] = __builtin_amdgcn_mfma_f32_16x16x32_bf16(wh_hi[4 + tl], hh, arh[tl], 0, 0, 0);
      arh[tl] = __builtin_amdgcn_mfma_f32_16x16x32_bf16(wh_hi[4 + tl], hl, arh[tl], 0, 0, 0);
      arh[tl] = __builtin_amdgcn_mfma_f32_16x16x32_bf16(wh_lo[4 + tl], hh, arh[tl], 0, 0, 0);
    }

    // Gates (batch = l15, hidden = tl*16 + quad*4 + rg).
#pragma unroll
    for (int tl = 0; tl < 2; ++tl) {
#pragma unroll
      for (int rg = 0; rg < 4; ++rg) {
        const float z  = sigmoid_fast(az[tl][rg]);
        const float r  = sigmoid_fast(ar[tl][rg]);
        const float g  = tanh_fast(axh[tl][rg] + r * arh[tl][rg]);
        const float hn = g + z * (hD[tl][rg] - g);   // = z*h + (1-z)*g
        hD[tl][rg] = mk ? hn : hD[tl][rg];
      }
    }
  }

#pragma unroll
  for (int tl = 0; tl < 2; ++tl)
    *(f32x4*)(out + (size_t)bRow * H3 + TOWER * ED + tl * 16 + quad * 4) = hD[tl];
}

__global__ void __launch_bounds__(64) gru_fused(
    const int* __restrict__ ids, const float* __restrict__ prices, const int* __restrict__ depts,
    const float* __restrict__ item_table, const float* __restrict__ price_table,
    const float* __restrict__ dept_table,
    const float* __restrict__ item_Wx, const float* __restrict__ item_Wh,
    const float* __restrict__ item_b,
    const float* __restrict__ price_Wx, const float* __restrict__ price_Wh,
    const float* __restrict__ price_b,
    const float* __restrict__ dept_Wx, const float* __restrict__ dept_Wh,
    const float* __restrict__ dept_b,
    const float* __restrict__ price_mean, const float* __restrict__ price_var,
    float* __restrict__ out) {
  const int tower = blockIdx.y;
  if (tower == 0) {
    tower_fused<0>(ids, prices, depts, item_table, item_Wx, item_Wh, item_b,
                   0.0f, 0.0f, out);
  } else if (tower == 1) {
    const float pm = price_mean[0];
    const float pr = rsqrtf(price_var[0]);
    tower_fused<1>(ids, prices, depts, price_table, price_Wx, price_Wh, price_b,
                   pm, pr, out);
  } else {
    tower_fused<2>(ids, prices, depts, dept_table, dept_Wx, dept_Wh, dept_b,
                   0.0f, 0.0f, out);
  }
}

extern "C" void kernel_launch(void* const* d_in, const int* in_sizes, int n_in,
                              void* d_out, int out_size, void* d_ws, size_t ws_size,
                              hipStream_t stream) {
  const int*   ids         = (const int*)d_in[0];
  const float* prices      = (const float*)d_in[1];
  const int*   depts       = (const int*)d_in[2];
  const float* item_table  = (const float*)d_in[3];
  const float* price_table = (const float*)d_in[4];
  const float* dept_table  = (const float*)d_in[5];
  const float* item_Wx     = (const float*)d_in[6];
  const float* item_Wh     = (const float*)d_in[7];
  const float* item_b      = (const float*)d_in[8];
  const float* price_Wx    = (const float*)d_in[9];
  const float* price_Wh    = (const float*)d_in[10];
  const float* price_b     = (const float*)d_in[11];
  const float* dept_Wx     = (const float*)d_in[12];
  const float* dept_Wh     = (const float*)d_in[13];
  const float* dept_b      = (const float*)d_in[14];
  const float* price_mean  = (const float*)d_in[15];
  const float* price_var   = (const float*)d_in[16];
  float* out = (float*)d_out;

  dim3 grid(NB / 16, 3, 1);   // one wave per block; 768 single-wave blocks
  gru_fused<<<grid, 64, 0, stream>>>(
      ids, prices, depts, item_table, price_table, dept_table,
      item_Wx, item_Wh, item_b, price_Wx, price_Wh, price_b,
      dept_Wx, dept_Wh, dept_b, price_mean, price_var, out);
}